// Round 11
// baseline (2508.836 us; speedup 1.0000x reference)
//
#include <hip/hip_runtime.h>
#include <cstdint>
#include <cstddef>

#define N_ROWS 16384
#define CDIM_C 512
#define HDIM_C 1024
#define FDIM_C 512
#define KMIX 5

typedef unsigned short u16;
typedef __attribute__((ext_vector_type(8))) short bf16x8;
typedef __attribute__((ext_vector_type(4))) float f32x4;

__device__ __forceinline__ u16 f2bf(float x) {
  unsigned u = __float_as_uint(x);
  unsigned r = (u + 0x7fffu + ((u >> 16) & 1u)) >> 16;
  return (u16)r;
}
__device__ __forceinline__ float bf2f(u16 h) {
  return __uint_as_float(((unsigned)h) << 16);
}

__device__ __forceinline__ void gload_lds16(const u16* g, u16* l) {
  __builtin_amdgcn_global_load_lds((const __attribute__((address_space(1))) void*)g,
                                   (__attribute__((address_space(3))) void*)l,
                                   16, 0, 0);
}

// ---------------------------------------------------------------------------
// split c (3-way bf16 Dekker split, exact 24-bit capture)
// ---------------------------------------------------------------------------
__global__ void split3_kernel(const float* __restrict__ x, u16* __restrict__ P0,
                              u16* __restrict__ P1, u16* __restrict__ P2, size_t n) {
  for (size_t i = (size_t)blockIdx.x * 256 + threadIdx.x; i < n; i += (size_t)gridDim.x * 256) {
    const float v = x[i];
    const u16 h = f2bf(v); const float hf = bf2f(h);
    const u16 m = f2bf(v - hf); const float mf = bf2f(m);
    P0[i] = h; P1[i] = m; P2[i] = f2bf(v - hf - mf);
  }
}

// ---------------------------------------------------------------------------
// transpose W[R][C] -> planes [C][R] with 2- or 3-way split.
// PERM: interleave mean/logvar columns (c<512 -> 2c, c>=512 -> 2(c-512)+1)
// ---------------------------------------------------------------------------
template <int NP, bool PERM>
__global__ void transp_split_kernel(const float* __restrict__ W, u16* __restrict__ P0,
                                    u16* __restrict__ P1, u16* __restrict__ P2,
                                    int R, int C) {
  __shared__ float t[32][33];
  const int bz = blockIdx.z;
  const float* Wz = W + (size_t)bz * R * C;
  const size_t oofs = (size_t)bz * R * C;
  const int r0 = blockIdx.x * 32, c0 = blockIdx.y * 32;
  const int tx = threadIdx.x, ty = threadIdx.y;  // (32,8)
#pragma unroll
  for (int i = 0; i < 4; ++i)
    t[ty + i * 8][tx] = Wz[(size_t)(r0 + ty + i * 8) * C + c0 + tx];
  __syncthreads();
#pragma unroll
  for (int i = 0; i < 4; ++i) {
    const int c_raw = c0 + ty + i * 8, r = r0 + tx;
    const int c = PERM ? ((c_raw < FDIM_C) ? (c_raw * 2) : ((c_raw - FDIM_C) * 2 + 1)) : c_raw;
    const float x = t[tx][ty + i * 8];
    const size_t idx = oofs + (size_t)c * R + r;
    const u16 h = f2bf(x);
    P0[idx] = h;
    const float hf = bf2f(h);
    const u16 m = f2bf(x - hf);
    P1[idx] = m;
    if (NP >= 3) {
      const float mf = bf2f(m);
      P2[idx] = f2bf(x - hf - mf);
    }
  }
}

// ---------------------------------------------------------------------------
// P-network 128x256-tile split GEMM: 512 threads = 8 waves (2M x 4N), each
// wave 64x64 (acc[4][4] = the proven 84-VGPR shape). 6 planes in LDS:
// A planes [4kb][128][8] @ 8KB, B planes [4kb][256][8] @ 16KB = 72KB total
// -> 2 blocks/CU = 16 waves/CU (4/SIMD, VGPR cap 128). Per CU-step:
// 2 x 8 x 96 = 1536 MFMA (+33% vs the 128x128 1152), 96 B staged/MFMA.
// ---------------------------------------------------------------------------
template <int NA, int NB, int NT, bool RELU, int OSPL>
__global__ __launch_bounds__(512, 4) void gemm_p512(
    const u16* __restrict__ A0, const u16* __restrict__ A1, const u16* __restrict__ A2,
    const u16* __restrict__ B0, const u16* __restrict__ B1, const u16* __restrict__ B2,
    const float* __restrict__ bias, float* __restrict__ outF,
    u16* __restrict__ O0, u16* __restrict__ O1, u16* __restrict__ O2,
    int Kd) {
  __shared__ __align__(16) u16 lds[36864];  // A p@p*4096, B q@12288+q*8192
  const int tid = threadIdx.x;
  const int lane = tid & 63;
  const int wave = tid >> 6;
  const int wm = wave >> 2, wn = wave & 3;
  const int kb = lane >> 4, rl = lane & 15;
  const int hi4 = lane >> 4;

  // bijective XCD swizzle (nwg = 512, divisible by 8)
  const int nwg = (int)(gridDim.x * gridDim.y);
  const int orig = (int)(blockIdx.y * gridDim.x + blockIdx.x);
  const int cpx = nwg >> 3;
  const int wg = (orig & 7) * cpx + (orig >> 3);
  const int col0 = (wg & 3) << 8;   // 4 col-tiles of 256
  const int row0 = (wg >> 2) << 7;  // 128 row-tiles of 128

  const u16* Ap[3] = {A0, A1, A2};
  const u16* Bp[3] = {B0, B1, B2};
  constexpr int TA[6] = {0, 0, 1, 1, 0, 2};
  constexpr int TB[6] = {0, 1, 0, 1, 2, 0};

  f32x4 acc[4][4] = {};
  const int nSteps = Kd >> 5;

  for (int kt = 0; kt < nSteps; ++kt) {
    const int k0 = kt << 5;
    __syncthreads();  // previous step's LDS reads done before overwrite
#pragma unroll
    for (int p = 0; p < NA; ++p) {  // A plane: 512 slots, 1 unit
      const int sbase = wave << 6;
      const int slot = sbase + lane;
      const int skb = slot >> 7, sr = slot & 127;
      gload_lds16(Ap[p] + (size_t)(row0 + sr) * Kd + k0 + skb * 8,
                  &lds[p * 4096 + sbase * 8]);
    }
#pragma unroll
    for (int q = 0; q < NB; ++q)  // B plane: 1024 slots, 2 units
#pragma unroll
      for (int it = 0; it < 2; ++it) {
        const int sbase = it * 512 + (wave << 6);
        const int slot = sbase + lane;
        const int skb = slot >> 8, sr = slot & 255;
        gload_lds16(Bp[q] + (size_t)(col0 + sr) * Kd + k0 + skb * 8,
                    &lds[12288 + q * 8192 + sbase * 8]);
      }
    __syncthreads();  // vmcnt(0) drain: staged tiles visible block-wide

    bf16x8 aF[NA][4];
    bf16x8 bF[NB][4];
#pragma unroll
    for (int p = 0; p < NA; ++p)
#pragma unroll
      for (int i = 0; i < 4; ++i)
        aF[p][i] = *(const bf16x8*)&lds[p * 4096 + (kb * 128 + wm * 64 + i * 16 + rl) * 8];
#pragma unroll
    for (int q = 0; q < NB; ++q)
#pragma unroll
      for (int j = 0; j < 4; ++j)
        bF[q][j] = *(const bf16x8*)&lds[12288 + q * 8192 + (kb * 256 + wn * 64 + j * 16 + rl) * 8];
#pragma unroll
    for (int t = 0; t < NT; ++t)
#pragma unroll
      for (int i = 0; i < 4; ++i)
#pragma unroll
        for (int j = 0; j < 4; ++j)
          acc[i][j] = __builtin_amdgcn_mfma_f32_16x16x32_bf16(
              aF[TA[t]][i], bF[TB[t]][j], acc[i][j], 0, 0, 0);
  }

  // epilogue: D layout col = lane&15, row = (lane>>4)*4 + r  [m89/m91 verified]
#pragma unroll
  for (int i = 0; i < 4; ++i)
#pragma unroll
    for (int j = 0; j < 4; ++j)
#pragma unroll
      for (int r = 0; r < 4; ++r) {
        const int row = row0 + wm * 64 + i * 16 + hi4 * 4 + r;
        const int col = col0 + wn * 64 + j * 16 + rl;
        float y = acc[i][j][r] + bias[col];
        if (RELU) y = fmaxf(y, 0.0f);
        const size_t idx = (size_t)row * HDIM_C + col;
        if constexpr (OSPL == 0) {
          outF[idx] = y;
        } else {
          const u16 h = f2bf(y);
          const float hf = bf2f(h);
          const u16 m = f2bf(y - hf);
          O0[idx] = h;
          O1[idx] = m;
          if constexpr (OSPL == 3) {
            const float mf = bf2f(m);
            O2[idx] = f2bf(y - hf - mf);
          }
        }
      }
}

// ---------------------------------------------------------------------------
// G-network 256x128-tile GEMM (R7-proven): BK=32, 4 waves each 128x64
// (acc[8][4]), aR[8]+bR[4] register blocks live, BPC=2 (~200 VGPR, no spill).
// Terms: (B0: A1, A0), (B1: A0). z-batched via element strides (0 strides +
// z=1 reproduces sequential behavior exactly).
// ---------------------------------------------------------------------------
template <bool RELU, int OSPL, int MIX>
__global__ __launch_bounds__(256, 2) void gemm_wide(
    const u16* __restrict__ A0, const u16* __restrict__ A1,
    const u16* __restrict__ B0, const u16* __restrict__ B1,
    const float* __restrict__ bias, float* __restrict__ outF,
    u16* __restrict__ O0, u16* __restrict__ O1,
    const float* __restrict__ noise_k, const float* __restrict__ wvec,
    float* __restrict__ mixout, int kidx, int Kd,
    size_t zsA, size_t zsB, size_t zsBias, size_t zsO) {
  __shared__ __align__(16) u16 lds[24576];  // A0@0, A1@8192, B0@16384, B1@20480
  const size_t zz = blockIdx.z;
  A0 += zz * zsA; A1 += zz * zsA;
  B0 += zz * zsB; B1 += zz * zsB;
  bias += zz * zsBias;
  O0 += zz * zsO; O1 += zz * zsO;

  const int tid = threadIdx.x;
  const int lane = tid & 63;
  const int wave = tid >> 6;
  const int wm = wave >> 1, wn = wave & 1;
  const int hi4 = lane >> 4, rl = lane & 15;

  // bijective XCD swizzle per z-slice (nwg = 512, divisible by 8)
  const int nwg = (int)(gridDim.x * gridDim.y);
  const int orig = (int)(blockIdx.y * gridDim.x + blockIdx.x);
  const int cpx = nwg >> 3;
  const int wg = (orig & 7) * cpx + (orig >> 3);
  const int col0 = (wg & 7) * 128;
  const int row0 = (wg >> 3) * 256;

  const u16* Ap[2] = {A0, A1};
  const u16* Bp[2] = {B0, B1};

  f32x4 acc[8][4] = {};
  bf16x8 aR[8], bR[4];
  const int nSteps = Kd >> 5;

  auto ldA = [&](int p) {
#pragma unroll
    for (int i = 0; i < 8; ++i)
      aR[i] = *(const bf16x8*)&lds[p * 8192 + (hi4 * 256 + wm * 128 + i * 16 + rl) * 8];
  };
  auto ldB = [&](int q) {
#pragma unroll
    for (int j = 0; j < 4; ++j)
      bR[j] = *(const bf16x8*)&lds[16384 + q * 4096 + (hi4 * 128 + wn * 64 + j * 16 + rl) * 8];
  };
  auto FMA = [&]() {
#pragma unroll
    for (int i = 0; i < 8; ++i)
#pragma unroll
      for (int j = 0; j < 4; ++j)
        acc[i][j] = __builtin_amdgcn_mfma_f32_16x16x32_bf16(aR[i], bR[j], acc[i][j], 0, 0, 0);
  };

  for (int kt = 0; kt < nSteps; ++kt) {
    const int ko = kt << 5;
    __syncthreads();  // previous step's LDS reads done before overwrite
#pragma unroll
    for (int p = 0; p < 2; ++p)  // A planes: [4kb][256r][8], 1024 slots each
#pragma unroll
      for (int it = 0; it < 4; ++it) {
        const int sbase = it * 256 + (wave << 6);
        const int slot = sbase + lane;
        gload_lds16(Ap[p] + (size_t)(row0 + (slot & 255)) * Kd + ko + (slot >> 8) * 8,
                    &lds[p * 8192 + sbase * 8]);
      }
#pragma unroll
    for (int q = 0; q < 2; ++q)  // B planes: [4kb][128r][8], 512 slots each
#pragma unroll
      for (int it = 0; it < 2; ++it) {
        const int sbase = it * 256 + (wave << 6);
        const int slot = sbase + lane;
        gload_lds16(Bp[q] + (size_t)(col0 + (slot & 127)) * Kd + ko + (slot >> 7) * 8,
                    &lds[16384 + q * 4096 + sbase * 8]);
      }
    __syncthreads();  // vmcnt(0) drain: staged tiles visible block-wide

    ldA(1); ldB(0); FMA();   // A1*B0
    ldA(0);         FMA();   // A0*B0 (reuse bR)
    ldB(1);         FMA();   // A0*B1 (reuse aR)
  }

  // epilogue: D layout col = lane&15, row = (lane>>4)*4 + r  [m89/m91 verified]
#pragma unroll
  for (int i = 0; i < 8; ++i)
#pragma unroll
    for (int j = 0; j < 4; ++j)
#pragma unroll
      for (int r = 0; r < 4; ++r) {
        const int row = row0 + wm * 128 + i * 16 + hi4 * 4 + r;
        const int col = col0 + wn * 64 + j * 16 + rl;
        if constexpr (MIX > 0) {
          // permuted cols: even = mean_f, odd = logvar_f, f = col>>1
          const int f = col >> 1;
          const int ocol = (col & 1) ? (f + FDIM_C) : f;
          const float y = acc[i][j][r] + bias[ocol];
          const float other = __shfl_xor(y, 1);
          if (!(lane & 1)) {
            const float sample = y + noise_k[(size_t)row * FDIM_C + f] * expf(0.5f * other);
            const float v = wvec[row * KMIX + kidx] * sample;
            float* op = &mixout[(size_t)row * FDIM_C + f];
            if constexpr (MIX == 1) *op = v; else *op += v;
          }
        } else {
          float y = acc[i][j][r] + bias[col];
          if (RELU) y = fmaxf(y, 0.0f);
          const size_t idx = (size_t)row * HDIM_C + col;
          const u16 h = f2bf(y);
          const float hf = bf2f(h);
          O0[idx] = h;
          O1[idx] = f2bf(y - hf);
          (void)outF;
        }
      }
}

// ---------------------------------------------------------------------------
// logits = h2 @ pw2 + pb2 ; softmax ; gumbel ; argmax ; mixture weights
// one wave per row, fp64 accumulation (argmax flip protection)
// ---------------------------------------------------------------------------
__global__ void p2_weights_kernel(const float* __restrict__ h2, const float* __restrict__ pw2,
                                  const float* __restrict__ pb2, const float* __restrict__ gu,
                                  float* __restrict__ w) {
  const int n = blockIdx.x * 4 + (threadIdx.x >> 6);
  const int lane = threadIdx.x & 63;
  const float* hrow = h2 + (size_t)n * HDIM_C;
  double acc[KMIX] = {0, 0, 0, 0, 0};
  const int c0 = lane * 16;
#pragma unroll
  for (int jj = 0; jj < 16; ++jj) {
    const int cc = c0 + jj;
    const double hv = (double)hrow[cc];
#pragma unroll
    for (int kk = 0; kk < KMIX; ++kk)
      acc[kk] += hv * (double)pw2[cc * KMIX + kk];
  }
#pragma unroll
  for (int offs = 32; offs >= 1; offs >>= 1)
#pragma unroll
    for (int kk = 0; kk < KMIX; ++kk)
      acc[kk] += __shfl_down(acc[kk], offs);
  if (lane == 0) {
    double lg[KMIX], mx = -1e300;
#pragma unroll
    for (int kk = 0; kk < KMIX; ++kk) {
      lg[kk] = acc[kk] + (double)pb2[kk];
      if (lg[kk] > mx) mx = lg[kk];
    }
    double e[KMIX], s = 0.0;
#pragma unroll
    for (int kk = 0; kk < KMIX; ++kk) { e[kk] = exp(lg[kk] - mx); s += e[kk]; }
    int idx = 0; double zb = -1e300;
#pragma unroll
    for (int kk = 0; kk < KMIX; ++kk) {
      const double ps = e[kk] / s;
      const double u = (double)gu[n * KMIX + kk];
      const double g = -log(-log(u + 1e-20) + 1e-20);
      const double zz = log(ps + 1e-20) + g;
      if (zz > zb) { zb = zz; idx = kk; }  // strict > keeps first index (jnp.argmax)
    }
#pragma unroll
    for (int kk = 0; kk < KMIX; ++kk)
      w[n * KMIX + kk] = (float)((e[kk] / s + (kk == idx ? 5.0 : 0.0)) / 6.0);
  }
}

// ---------------------------------------------------------------------------
extern "C" void kernel_launch(void* const* d_in, const int* in_sizes, int n_in,
                              void* d_out, int out_size, void* d_ws, size_t ws_size,
                              hipStream_t stream) {
  const float* c   = (const float*)d_in[0];
  const float* noise = (const float*)d_in[2];
  const float* gu  = (const float*)d_in[3];
  const float* pw0 = (const float*)d_in[4];
  const float* pb0 = (const float*)d_in[5];
  const float* pw1 = (const float*)d_in[6];
  const float* pb1 = (const float*)d_in[7];
  const float* pw2 = (const float*)d_in[8];
  const float* pb2 = (const float*)d_in[9];
  const float* gw0 = (const float*)d_in[10];
  const float* gb0 = (const float*)d_in[11];
  const float* gw1 = (const float*)d_in[12];
  const float* gb1 = (const float*)d_in[13];
  const float* gw2 = (const float*)d_in[14];
  const float* gb2 = (const float*)d_in[15];
  float* out = (float*)d_out;

  char* ws = (char*)d_ws;
  size_t off = 0;
  auto alloc = [&](size_t bytes) -> char* {
    off = (off + 255) & ~(size_t)255;
    char* p = ws + off;
    off += bytes;
    return p;
  };

  const size_t NCp = (size_t)N_ROWS * CDIM_C * 2;   // 16 MB
  const size_t NHp = (size_t)N_ROWS * HDIM_C * 2;   // 32 MB
  const size_t NHe = (size_t)N_ROWS * HDIM_C;       // elements per expert-plane
  u16* cH = (u16*)alloc(NCp);
  u16* cM = (u16*)alloc(NCp);
  u16* cL = (u16*)alloc(NCp);
  u16* pw0T0 = (u16*)alloc((size_t)CDIM_C * HDIM_C * 2);
  u16* pw0T1 = (u16*)alloc((size_t)CDIM_C * HDIM_C * 2);
  u16* pw0T2 = (u16*)alloc((size_t)CDIM_C * HDIM_C * 2);
  u16* pw1T0 = (u16*)alloc((size_t)HDIM_C * HDIM_C * 2);
  u16* pw1T1 = (u16*)alloc((size_t)HDIM_C * HDIM_C * 2);
  u16* pw1T2 = (u16*)alloc((size_t)HDIM_C * HDIM_C * 2);
  u16* hH = (u16*)alloc(NHp);
  u16* hM = (u16*)alloc(NHp);
  u16* hL = (u16*)alloc(NHp);
  float* h2 = (float*)alloc((size_t)N_ROWS * HDIM_C * 4);
  float* wbuf = (float*)alloc((size_t)N_ROWS * KMIX * 4);
  u16* gw0T0 = (u16*)alloc((size_t)KMIX * CDIM_C * HDIM_C * 2);
  u16* gw0T1 = (u16*)alloc((size_t)KMIX * CDIM_C * HDIM_C * 2);
  u16* gw1T0 = (u16*)alloc((size_t)KMIX * HDIM_C * HDIM_C * 2);
  u16* gw1T1 = (u16*)alloc((size_t)KMIX * HDIM_C * HDIM_C * 2);
  u16* gw2T0 = (u16*)alloc((size_t)KMIX * HDIM_C * HDIM_C * 2);
  u16* gw2T1 = (u16*)alloc((size_t)KMIX * HDIM_C * HDIM_C * 2);
  u16* g2b_seq = (u16*)alloc(NHp);
  const size_t base_off = off;
  // batched-path buffers (per-expert g1/g2 planes)
  u16* g1z0 = (u16*)alloc(KMIX * NHp);
  u16* g1z1 = (u16*)alloc(KMIX * NHp);
  u16* g2z0 = (u16*)alloc(KMIX * NHp);
  u16* g2z1 = (u16*)alloc(KMIX * NHp);
  const bool batched = (off <= ws_size);
  off = base_off;
  (void)in_sizes; (void)n_in; (void)out_size;

  // ---- prep ----
  split3_kernel<<<2048, 256, 0, stream>>>(c, cH, cM, cL, (size_t)N_ROWS * CDIM_C);
  transp_split_kernel<3, false><<<dim3(CDIM_C / 32, HDIM_C / 32, 1), dim3(32, 8), 0, stream>>>(
      pw0, pw0T0, pw0T1, pw0T2, CDIM_C, HDIM_C);
  transp_split_kernel<3, false><<<dim3(HDIM_C / 32, HDIM_C / 32, 1), dim3(32, 8), 0, stream>>>(
      pw1, pw1T0, pw1T1, pw1T2, HDIM_C, HDIM_C);
  transp_split_kernel<2, false><<<dim3(CDIM_C / 32, HDIM_C / 32, KMIX), dim3(32, 8), 0, stream>>>(
      gw0, gw0T0, gw0T1, nullptr, CDIM_C, HDIM_C);
  transp_split_kernel<2, false><<<dim3(HDIM_C / 32, HDIM_C / 32, KMIX), dim3(32, 8), 0, stream>>>(
      gw1, gw1T0, gw1T1, nullptr, HDIM_C, HDIM_C);
  transp_split_kernel<2, true><<<dim3(HDIM_C / 32, HDIM_C / 32, KMIX), dim3(32, 8), 0, stream>>>(
      gw2, gw2T0, gw2T1, nullptr, HDIM_C, HDIM_C);

  const dim3 ggP5(HDIM_C / 256, N_ROWS / 128);     // (4, 128) = 512 wgs
  const dim3 ggW(HDIM_C / 128, N_ROWS / 256);      // (8, 64)  = 512 wgs
  const dim3 ggWz(HDIM_C / 128, N_ROWS / 256, KMIX);

  // ---- P network (6-pass 128x256 wide-block, ~fp32-exact for argmax) ----
  gemm_p512<3, 3, 6, true, 3><<<ggP5, 512, 0, stream>>>(
      cH, cM, cL, pw0T0, pw0T1, pw0T2, pb0, nullptr, hH, hM, hL, CDIM_C);
  gemm_p512<3, 3, 6, true, 0><<<ggP5, 512, 0, stream>>>(
      hH, hM, hL, pw1T0, pw1T1, pw1T2, pb1, h2, nullptr, nullptr, nullptr, HDIM_C);
  p2_weights_kernel<<<N_ROWS / 4, 256, 0, stream>>>(h2, pw2, pb2, gu, wbuf);

  // ---- G network + fused mix epilogue ----
  if (batched) {
    gemm_wide<true, 2, 0><<<ggWz, 256, 0, stream>>>(
        cH, cM, gw0T0, gw0T1, gb0, nullptr, g1z0, g1z1,
        nullptr, nullptr, nullptr, 0, CDIM_C,
        0, (size_t)CDIM_C * HDIM_C, HDIM_C, NHe);
    gemm_wide<true, 2, 0><<<ggWz, 256, 0, stream>>>(
        g1z0, g1z1, gw1T0, gw1T1, gb1, nullptr, g2z0, g2z1,
        nullptr, nullptr, nullptr, 0, HDIM_C,
        NHe, (size_t)HDIM_C * HDIM_C, HDIM_C, NHe);
    for (int k = 0; k < KMIX; ++k) {
      if (k == 0)
        gemm_wide<false, 0, 1><<<ggW, 256, 0, stream>>>(
            g2z0 + (size_t)k * NHe, g2z1 + (size_t)k * NHe,
            gw2T0 + (size_t)k * HDIM_C * HDIM_C, gw2T1 + (size_t)k * HDIM_C * HDIM_C,
            gb2 + k * HDIM_C, nullptr, nullptr, nullptr,
            noise + (size_t)k * N_ROWS * FDIM_C, wbuf, out, k, HDIM_C, 0, 0, 0, 0);
      else
        gemm_wide<false, 0, 2><<<ggW, 256, 0, stream>>>(
            g2z0 + (size_t)k * NHe, g2z1 + (size_t)k * NHe,
            gw2T0 + (size_t)k * HDIM_C * HDIM_C, gw2T1 + (size_t)k * HDIM_C * HDIM_C,
            gb2 + k * HDIM_C, nullptr, nullptr, nullptr,
            noise + (size_t)k * N_ROWS * FDIM_C, wbuf, out, k, HDIM_C, 0, 0, 0, 0);
    }
  } else {
    u16* g1a = hH;
    u16* g1b = hM;
    u16* g2a = hL;
    u16* g2b = g2b_seq;
    for (int k = 0; k < KMIX; ++k) {
      gemm_wide<true, 2, 0><<<ggW, 256, 0, stream>>>(
          cH, cM,
          gw0T0 + (size_t)k * CDIM_C * HDIM_C, gw0T1 + (size_t)k * CDIM_C * HDIM_C,
          gb0 + k * HDIM_C, nullptr, g1a, g1b,
          nullptr, nullptr, nullptr, 0, CDIM_C, 0, 0, 0, 0);
      gemm_wide<true, 2, 0><<<ggW, 256, 0, stream>>>(
          g1a, g1b,
          gw1T0 + (size_t)k * HDIM_C * HDIM_C, gw1T1 + (size_t)k * HDIM_C * HDIM_C,
          gb1 + k * HDIM_C, nullptr, g2a, g2b,
          nullptr, nullptr, nullptr, 0, HDIM_C, 0, 0, 0, 0);
      if (k == 0)
        gemm_wide<false, 0, 1><<<ggW, 256, 0, stream>>>(
            g2a, g2b,
            gw2T0 + (size_t)k * HDIM_C * HDIM_C, gw2T1 + (size_t)k * HDIM_C * HDIM_C,
            gb2 + k * HDIM_C, nullptr, nullptr, nullptr,
            noise + (size_t)k * N_ROWS * FDIM_C, wbuf, out, k, HDIM_C, 0, 0, 0, 0);
      else
        gemm_wide<false, 0, 2><<<ggW, 256, 0, stream>>>(
            g2a, g2b,
            gw2T0 + (size_t)k * HDIM_C * HDIM_C, gw2T1 + (size_t)k * HDIM_C * HDIM_C,
            gb2 + k * HDIM_C, nullptr, nullptr, nullptr,
            noise + (size_t)k * N_ROWS * FDIM_C, wbuf, out, k, HDIM_C, 0, 0, 0, 0);
    }
  }
}

// Round 12
// 2344.809 us; speedup vs baseline: 1.0700x; 1.0700x over previous
//
#include <hip/hip_runtime.h>
#include <cstdint>
#include <cstddef>

#define N_ROWS 16384
#define CDIM_C 512
#define HDIM_C 1024
#define FDIM_C 512
#define KMIX 5

typedef unsigned short u16;
typedef __attribute__((ext_vector_type(8))) short bf16x8;
typedef __attribute__((ext_vector_type(4))) float f32x4;

__device__ __forceinline__ u16 f2bf(float x) {
  unsigned u = __float_as_uint(x);
  unsigned r = (u + 0x7fffu + ((u >> 16) & 1u)) >> 16;
  return (u16)r;
}
__device__ __forceinline__ float bf2f(u16 h) {
  return __uint_as_float(((unsigned)h) << 16);
}

__device__ __forceinline__ void gload_lds16(const u16* g, u16* l) {
  __builtin_amdgcn_global_load_lds((const __attribute__((address_space(1))) void*)g,
                                   (__attribute__((address_space(3))) void*)l,
                                   16, 0, 0);
}

// ---------------------------------------------------------------------------
// split c (3-way bf16 Dekker split, exact 24-bit capture)
// ---------------------------------------------------------------------------
__global__ void split3_kernel(const float* __restrict__ x, u16* __restrict__ P0,
                              u16* __restrict__ P1, u16* __restrict__ P2, size_t n) {
  for (size_t i = (size_t)blockIdx.x * 256 + threadIdx.x; i < n; i += (size_t)gridDim.x * 256) {
    const float v = x[i];
    const u16 h = f2bf(v); const float hf = bf2f(h);
    const u16 m = f2bf(v - hf); const float mf = bf2f(m);
    P0[i] = h; P1[i] = m; P2[i] = f2bf(v - hf - mf);
  }
}

// ---------------------------------------------------------------------------
// transpose W[R][C] -> planes [C][R] with 2- or 3-way split.
// PERM: interleave mean/logvar columns (c<512 -> 2c, c>=512 -> 2(c-512)+1)
// ---------------------------------------------------------------------------
template <int NP, bool PERM>
__global__ void transp_split_kernel(const float* __restrict__ W, u16* __restrict__ P0,
                                    u16* __restrict__ P1, u16* __restrict__ P2,
                                    int R, int C) {
  __shared__ float t[32][33];
  const int bz = blockIdx.z;
  const float* Wz = W + (size_t)bz * R * C;
  const size_t oofs = (size_t)bz * R * C;
  const int r0 = blockIdx.x * 32, c0 = blockIdx.y * 32;
  const int tx = threadIdx.x, ty = threadIdx.y;  // (32,8)
#pragma unroll
  for (int i = 0; i < 4; ++i)
    t[ty + i * 8][tx] = Wz[(size_t)(r0 + ty + i * 8) * C + c0 + tx];
  __syncthreads();
#pragma unroll
  for (int i = 0; i < 4; ++i) {
    const int c_raw = c0 + ty + i * 8, r = r0 + tx;
    const int c = PERM ? ((c_raw < FDIM_C) ? (c_raw * 2) : ((c_raw - FDIM_C) * 2 + 1)) : c_raw;
    const float x = t[tx][ty + i * 8];
    const size_t idx = oofs + (size_t)c * R + r;
    const u16 h = f2bf(x);
    P0[idx] = h;
    const float hf = bf2f(h);
    const u16 m = f2bf(x - hf);
    P1[idx] = m;
    if (NP >= 3) {
      const float mf = bf2f(m);
      P2[idx] = f2bf(x - hf - mf);
    }
  }
}

// ---------------------------------------------------------------------------
// R2/R7-proven 128x128 split-precision GEMM (P network): BK=32, 4 waves (2x2),
// 4x4 frags/wave, 6 planes in LDS, 96 MFMA/wave/step, 3 blocks/CU (84 VGPR).
// Measured 877 TF — the structure's unique density x occupancy sweet spot.
// ---------------------------------------------------------------------------
template <int NA, int NB, int NT, bool RELU, int OSPL, int BPC>
__global__ __launch_bounds__(256, BPC) void gemm_split(
    const u16* __restrict__ A0, const u16* __restrict__ A1, const u16* __restrict__ A2,
    const u16* __restrict__ B0, const u16* __restrict__ B1, const u16* __restrict__ B2,
    const float* __restrict__ bias, float* __restrict__ outF,
    u16* __restrict__ O0, u16* __restrict__ O1, u16* __restrict__ O2,
    int Nc, int Kd) {
  __shared__ u16 lds[(NA + NB) * 4096];  // per plane: [4 kb][128 rows][8 bf16] = 8 KB
  const int tid = threadIdx.x;
  const int lane = tid & 63;
  const int wave = tid >> 6;
  const int wm = wave >> 1, wn = wave & 1;

  // bijective XCD swizzle (nwg = 1024, divisible by 8)
  const int nwg = (int)(gridDim.x * gridDim.y);
  const int orig = (int)(blockIdx.y * gridDim.x + blockIdx.x);
  const int cpx = nwg >> 3;
  const int wg = (orig & 7) * cpx + (orig >> 3);
  const int col0 = (wg & 7) * 128;
  const int row0 = (wg >> 3) * 128;

  const u16* Ap[3] = {A0, A1, A2};
  const u16* Bp[3] = {B0, B1, B2};
  constexpr int TA[6] = {0, 0, 1, 1, 0, 2};
  constexpr int TB[6] = {0, 1, 0, 1, 2, 0};

  f32x4 acc[4][4] = {};
  const int kb = lane >> 4;
  const int rl = lane & 15;
  const int nSteps = Kd >> 5;

  for (int kt = 0; kt < nSteps; ++kt) {
    const int k0 = kt << 5;
    __syncthreads();
#pragma unroll
    for (int p = 0; p < NA + NB; ++p) {
      const u16* gp = (p < NA) ? Ap[p] : Bp[p - NA];
      const int rb = (p < NA) ? row0 : col0;
      u16* lbase = &lds[p * 4096];
#pragma unroll
      for (int it = 0; it < 2; ++it) {
        const int sbase = it * 256 + wave * 64;
        const int slot = sbase + lane;
        const int skb = slot >> 7;
        const int sr = slot & 127;
        gload_lds16(gp + (size_t)(rb + sr) * Kd + (k0 + skb * 8), lbase + sbase * 8);
      }
    }
    __syncthreads();

    bf16x8 aF[NA][4];
    bf16x8 bF[NB][4];
#pragma unroll
    for (int p = 0; p < NA; ++p)
#pragma unroll
      for (int i = 0; i < 4; ++i)
        aF[p][i] = *(const bf16x8*)&lds[p * 4096 + (kb * 128 + wm * 64 + i * 16 + rl) * 8];
#pragma unroll
    for (int p = 0; p < NB; ++p)
#pragma unroll
      for (int j = 0; j < 4; ++j)
        bF[p][j] = *(const bf16x8*)&lds[(NA + p) * 4096 + (kb * 128 + wn * 64 + j * 16 + rl) * 8];
#pragma unroll
    for (int t = 0; t < NT; ++t)
#pragma unroll
      for (int i = 0; i < 4; ++i)
#pragma unroll
        for (int j = 0; j < 4; ++j)
          acc[i][j] = __builtin_amdgcn_mfma_f32_16x16x32_bf16(
              aF[TA[t]][i], bF[TB[t]][j], acc[i][j], 0, 0, 0);
  }

  // epilogue: D layout col = lane&15, row = (lane>>4)*4 + r  [m89/m91 verified]
#pragma unroll
  for (int i = 0; i < 4; ++i)
#pragma unroll
    for (int j = 0; j < 4; ++j)
#pragma unroll
      for (int r = 0; r < 4; ++r) {
        const int row = row0 + wm * 64 + i * 16 + (lane >> 4) * 4 + r;
        const int col = col0 + wn * 64 + j * 16 + (lane & 15);
        float y = acc[i][j][r] + bias[col];
        if (RELU) y = fmaxf(y, 0.0f);
        const size_t idx = (size_t)row * Nc + col;
        if constexpr (OSPL == 0) {
          outF[idx] = y;
        } else {
          const u16 h = f2bf(y);
          const float hf = bf2f(h);
          const u16 m = f2bf(y - hf);
          O0[idx] = h;
          O1[idx] = m;
          if constexpr (OSPL == 3) {
            const float mf = bf2f(m);
            O2[idx] = f2bf(y - hf - mf);
          }
        }
      }
}

// ---------------------------------------------------------------------------
// G-network 256x128-tile GEMM (R7-proven): BK=32, 4 waves each 128x64
// (acc[8][4]), aR[8]+bR[4] register blocks live, BPC=2 (~200 VGPR, no spill).
// Terms: (B0: A1, A0), (B1: A0) — each plane register block loaded once.
// NT=3/4-plane GEMMs are structurally pinned at 768 MFMA/CU-step (R2/R7/R8/R9
// all converge there); this is the best-measured realization (~730 TF).
// ---------------------------------------------------------------------------
template <bool RELU, int OSPL, int MIX>
__global__ __launch_bounds__(256, 2) void gemm_wide(
    const u16* __restrict__ A0, const u16* __restrict__ A1,
    const u16* __restrict__ B0, const u16* __restrict__ B1,
    const float* __restrict__ bias, float* __restrict__ outF,
    u16* __restrict__ O0, u16* __restrict__ O1,
    const float* __restrict__ noise_k, const float* __restrict__ wvec,
    float* __restrict__ mixout, int kidx, int Kd) {
  __shared__ __align__(16) u16 lds[24576];  // A0@0, A1@8192, B0@16384, B1@20480
  const int tid = threadIdx.x;
  const int lane = tid & 63;
  const int wave = tid >> 6;
  const int wm = wave >> 1, wn = wave & 1;
  const int hi4 = lane >> 4, rl = lane & 15;

  // bijective XCD swizzle (nwg = 512, divisible by 8)
  const int nwg = (int)(gridDim.x * gridDim.y);
  const int orig = (int)(blockIdx.y * gridDim.x + blockIdx.x);
  const int cpx = nwg >> 3;
  const int wg = (orig & 7) * cpx + (orig >> 3);
  const int col0 = (wg & 7) * 128;
  const int row0 = (wg >> 3) * 256;

  const u16* Ap[2] = {A0, A1};
  const u16* Bp[2] = {B0, B1};

  f32x4 acc[8][4] = {};
  bf16x8 aR[8], bR[4];
  const int nSteps = Kd >> 5;

  auto ldA = [&](int p) {
#pragma unroll
    for (int i = 0; i < 8; ++i)
      aR[i] = *(const bf16x8*)&lds[p * 8192 + (hi4 * 256 + wm * 128 + i * 16 + rl) * 8];
  };
  auto ldB = [&](int q) {
#pragma unroll
    for (int j = 0; j < 4; ++j)
      bR[j] = *(const bf16x8*)&lds[16384 + q * 4096 + (hi4 * 128 + wn * 64 + j * 16 + rl) * 8];
  };
  auto FMA = [&]() {
#pragma unroll
    for (int i = 0; i < 8; ++i)
#pragma unroll
      for (int j = 0; j < 4; ++j)
        acc[i][j] = __builtin_amdgcn_mfma_f32_16x16x32_bf16(aR[i], bR[j], acc[i][j], 0, 0, 0);
  };

  for (int kt = 0; kt < nSteps; ++kt) {
    const int ko = kt << 5;
    __syncthreads();  // previous step's LDS reads done before overwrite
#pragma unroll
    for (int p = 0; p < 2; ++p)  // A planes: [4kb][256r][8], 1024 slots each
#pragma unroll
      for (int it = 0; it < 4; ++it) {
        const int sbase = it * 256 + (wave << 6);
        const int slot = sbase + lane;
        gload_lds16(Ap[p] + (size_t)(row0 + (slot & 255)) * Kd + ko + (slot >> 8) * 8,
                    &lds[p * 8192 + sbase * 8]);
      }
#pragma unroll
    for (int q = 0; q < 2; ++q)  // B planes: [4kb][128r][8], 512 slots each
#pragma unroll
      for (int it = 0; it < 2; ++it) {
        const int sbase = it * 256 + (wave << 6);
        const int slot = sbase + lane;
        gload_lds16(Bp[q] + (size_t)(col0 + (slot & 127)) * Kd + ko + (slot >> 7) * 8,
                    &lds[16384 + q * 4096 + sbase * 8]);
      }
    __syncthreads();  // vmcnt(0) drain: staged tiles visible block-wide

    ldA(1); ldB(0); FMA();   // A1*B0
    ldA(0);         FMA();   // A0*B0 (reuse bR)
    ldB(1);         FMA();   // A0*B1 (reuse aR)
  }

  // epilogue: D layout col = lane&15, row = (lane>>4)*4 + r  [m89/m91 verified]
#pragma unroll
  for (int i = 0; i < 8; ++i)
#pragma unroll
    for (int j = 0; j < 4; ++j)
#pragma unroll
      for (int r = 0; r < 4; ++r) {
        const int row = row0 + wm * 128 + i * 16 + hi4 * 4 + r;
        const int col = col0 + wn * 64 + j * 16 + rl;
        if constexpr (MIX > 0) {
          // permuted cols: even = mean_f, odd = logvar_f, f = col>>1
          const int f = col >> 1;
          const int ocol = (col & 1) ? (f + FDIM_C) : f;
          const float y = acc[i][j][r] + bias[ocol];
          const float other = __shfl_xor(y, 1);
          if (!(lane & 1)) {
            const float sample = y + noise_k[(size_t)row * FDIM_C + f] * expf(0.5f * other);
            const float v = wvec[row * KMIX + kidx] * sample;
            float* op = &mixout[(size_t)row * FDIM_C + f];
            if constexpr (MIX == 1) *op = v; else *op += v;
          }
        } else {
          float y = acc[i][j][r] + bias[col];
          if (RELU) y = fmaxf(y, 0.0f);
          const size_t idx = (size_t)row * HDIM_C + col;
          const u16 h = f2bf(y);
          const float hf = bf2f(h);
          O0[idx] = h;
          O1[idx] = f2bf(y - hf);
          (void)outF;
        }
      }
}

// ---------------------------------------------------------------------------
// logits = h2 @ pw2 + pb2 ; softmax ; gumbel ; argmax ; mixture weights
// one wave per row, fp64 accumulation (argmax flip protection)
// ---------------------------------------------------------------------------
__global__ void p2_weights_kernel(const float* __restrict__ h2, const float* __restrict__ pw2,
                                  const float* __restrict__ pb2, const float* __restrict__ gu,
                                  float* __restrict__ w) {
  const int n = blockIdx.x * 4 + (threadIdx.x >> 6);
  const int lane = threadIdx.x & 63;
  const float* hrow = h2 + (size_t)n * HDIM_C;
  double acc[KMIX] = {0, 0, 0, 0, 0};
  const int c0 = lane * 16;
#pragma unroll
  for (int jj = 0; jj < 16; ++jj) {
    const int cc = c0 + jj;
    const double hv = (double)hrow[cc];
#pragma unroll
    for (int kk = 0; kk < KMIX; ++kk)
      acc[kk] += hv * (double)pw2[cc * KMIX + kk];
  }
#pragma unroll
  for (int offs = 32; offs >= 1; offs >>= 1)
#pragma unroll
    for (int kk = 0; kk < KMIX; ++kk)
      acc[kk] += __shfl_down(acc[kk], offs);
  if (lane == 0) {
    double lg[KMIX], mx = -1e300;
#pragma unroll
    for (int kk = 0; kk < KMIX; ++kk) {
      lg[kk] = acc[kk] + (double)pb2[kk];
      if (lg[kk] > mx) mx = lg[kk];
    }
    double e[KMIX], s = 0.0;
#pragma unroll
    for (int kk = 0; kk < KMIX; ++kk) { e[kk] = exp(lg[kk] - mx); s += e[kk]; }
    int idx = 0; double zb = -1e300;
#pragma unroll
    for (int kk = 0; kk < KMIX; ++kk) {
      const double ps = e[kk] / s;
      const double u = (double)gu[n * KMIX + kk];
      const double g = -log(-log(u + 1e-20) + 1e-20);
      const double zz = log(ps + 1e-20) + g;
      if (zz > zb) { zb = zz; idx = kk; }  // strict > keeps first index (jnp.argmax)
    }
#pragma unroll
    for (int kk = 0; kk < KMIX; ++kk)
      w[n * KMIX + kk] = (float)((e[kk] / s + (kk == idx ? 5.0 : 0.0)) / 6.0);
  }
}

// ---------------------------------------------------------------------------
extern "C" void kernel_launch(void* const* d_in, const int* in_sizes, int n_in,
                              void* d_out, int out_size, void* d_ws, size_t ws_size,
                              hipStream_t stream) {
  const float* c   = (const float*)d_in[0];
  const float* noise = (const float*)d_in[2];
  const float* gu  = (const float*)d_in[3];
  const float* pw0 = (const float*)d_in[4];
  const float* pb0 = (const float*)d_in[5];
  const float* pw1 = (const float*)d_in[6];
  const float* pb1 = (const float*)d_in[7];
  const float* pw2 = (const float*)d_in[8];
  const float* pb2 = (const float*)d_in[9];
  const float* gw0 = (const float*)d_in[10];
  const float* gb0 = (const float*)d_in[11];
  const float* gw1 = (const float*)d_in[12];
  const float* gb1 = (const float*)d_in[13];
  const float* gw2 = (const float*)d_in[14];
  const float* gb2 = (const float*)d_in[15];
  float* out = (float*)d_out;

  char* ws = (char*)d_ws;
  size_t off = 0;
  auto alloc = [&](size_t bytes) -> char* {
    off = (off + 255) & ~(size_t)255;
    char* p = ws + off;
    off += bytes;
    return p;
  };

  const size_t NCp = (size_t)N_ROWS * CDIM_C * 2;
  const size_t NHp = (size_t)N_ROWS * HDIM_C * 2;
  u16* cH = (u16*)alloc(NCp);
  u16* cM = (u16*)alloc(NCp);
  u16* cL = (u16*)alloc(NCp);
  u16* pw0T0 = (u16*)alloc((size_t)CDIM_C * HDIM_C * 2);
  u16* pw0T1 = (u16*)alloc((size_t)CDIM_C * HDIM_C * 2);
  u16* pw0T2 = (u16*)alloc((size_t)CDIM_C * HDIM_C * 2);
  u16* pw1T0 = (u16*)alloc((size_t)HDIM_C * HDIM_C * 2);
  u16* pw1T1 = (u16*)alloc((size_t)HDIM_C * HDIM_C * 2);
  u16* pw1T2 = (u16*)alloc((size_t)HDIM_C * HDIM_C * 2);
  u16* hH = (u16*)alloc(NHp);
  u16* hM = (u16*)alloc(NHp);
  u16* hL = (u16*)alloc(NHp);
  float* h2 = (float*)alloc((size_t)N_ROWS * HDIM_C * 4);
  float* wbuf = (float*)alloc((size_t)N_ROWS * KMIX * 4);
  u16* gw0T0 = (u16*)alloc((size_t)KMIX * CDIM_C * HDIM_C * 2);
  u16* gw0T1 = (u16*)alloc((size_t)KMIX * CDIM_C * HDIM_C * 2);
  u16* gw1T0 = (u16*)alloc((size_t)KMIX * HDIM_C * HDIM_C * 2);
  u16* gw1T1 = (u16*)alloc((size_t)KMIX * HDIM_C * HDIM_C * 2);
  u16* gw2T0 = (u16*)alloc((size_t)KMIX * HDIM_C * HDIM_C * 2);
  u16* gw2T1 = (u16*)alloc((size_t)KMIX * HDIM_C * HDIM_C * 2);
  u16* g2b = (u16*)alloc(NHp);
  u16* g1a = hH;   // h planes dead after P1
  u16* g1b = hM;
  u16* g2a = hL;
  (void)ws_size; (void)in_sizes; (void)n_in; (void)out_size;

  // ---- prep ----
  split3_kernel<<<2048, 256, 0, stream>>>(c, cH, cM, cL, (size_t)N_ROWS * CDIM_C);
  transp_split_kernel<3, false><<<dim3(CDIM_C / 32, HDIM_C / 32, 1), dim3(32, 8), 0, stream>>>(
      pw0, pw0T0, pw0T1, pw0T2, CDIM_C, HDIM_C);
  transp_split_kernel<3, false><<<dim3(HDIM_C / 32, HDIM_C / 32, 1), dim3(32, 8), 0, stream>>>(
      pw1, pw1T0, pw1T1, pw1T2, HDIM_C, HDIM_C);
  transp_split_kernel<2, false><<<dim3(CDIM_C / 32, HDIM_C / 32, KMIX), dim3(32, 8), 0, stream>>>(
      gw0, gw0T0, gw0T1, nullptr, CDIM_C, HDIM_C);
  transp_split_kernel<2, false><<<dim3(HDIM_C / 32, HDIM_C / 32, KMIX), dim3(32, 8), 0, stream>>>(
      gw1, gw1T0, gw1T1, nullptr, HDIM_C, HDIM_C);
  transp_split_kernel<2, true><<<dim3(HDIM_C / 32, HDIM_C / 32, KMIX), dim3(32, 8), 0, stream>>>(
      gw2, gw2T0, gw2T1, nullptr, HDIM_C, HDIM_C);

  const dim3 ggP(HDIM_C / 128, N_ROWS / 128);  // (8, 128) = 1024 wgs
  const dim3 ggW(HDIM_C / 128, N_ROWS / 256);  // (8, 64)  = 512 wgs

  // ---- P network (6-pass, ~fp32-exact for argmax safety) ----
  gemm_split<3, 3, 6, true, 3, 3><<<ggP, 256, 0, stream>>>(
      cH, cM, cL, pw0T0, pw0T1, pw0T2, pb0, nullptr, hH, hM, hL, HDIM_C, CDIM_C);
  gemm_split<3, 3, 6, true, 0, 3><<<ggP, 256, 0, stream>>>(
      hH, hM, hL, pw1T0, pw1T1, pw1T2, pb1, h2, nullptr, nullptr, nullptr, HDIM_C, HDIM_C);
  p2_weights_kernel<<<N_ROWS / 4, 256, 0, stream>>>(h2, pw2, pb2, gu, wbuf);

  // ---- G network (256x128 wide tile) + fused mix epilogue ----
  for (int k = 0; k < KMIX; ++k) {
    gemm_wide<true, 2, 0><<<ggW, 256, 0, stream>>>(
        cH, cM,
        gw0T0 + (size_t)k * CDIM_C * HDIM_C, gw0T1 + (size_t)k * CDIM_C * HDIM_C,
        gb0 + k * HDIM_C, nullptr, g1a, g1b,
        nullptr, nullptr, nullptr, 0, CDIM_C);
    gemm_wide<true, 2, 0><<<ggW, 256, 0, stream>>>(
        g1a, g1b,
        gw1T0 + (size_t)k * HDIM_C * HDIM_C, gw1T1 + (size_t)k * HDIM_C * HDIM_C,
        gb1 + k * HDIM_C, nullptr, g2a, g2b,
        nullptr, nullptr, nullptr, 0, HDIM_C);
    if (k == 0)
      gemm_wide<false, 0, 1><<<ggW, 256, 0, stream>>>(
          g2a, g2b,
          gw2T0 + (size_t)k * HDIM_C * HDIM_C, gw2T1 + (size_t)k * HDIM_C * HDIM_C,
          gb2 + k * HDIM_C, nullptr, nullptr, nullptr,
          noise + (size_t)k * N_ROWS * FDIM_C, wbuf, out, k, HDIM_C);
    else
      gemm_wide<false, 0, 2><<<ggW, 256, 0, stream>>>(
          g2a, g2b,
          gw2T0 + (size_t)k * HDIM_C * HDIM_C, gw2T1 + (size_t)k * HDIM_C * HDIM_C,
          gb2 + k * HDIM_C, nullptr, nullptr, nullptr,
          noise + (size_t)k * N_ROWS * FDIM_C, wbuf, out, k, HDIM_C);
  }
}